// Round 6
// baseline (129.513 us; speedup 1.0000x reference)
//
#include <hip/hip_runtime.h>
#include <hip/hip_bf16.h>
#include <hip/hip_fp16.h>

// Problem constants
#define BATCH 256
#define IN_DIM 1024
#define NKER 100
#define DKER 50
#define ACT_N 5000           // NKER*DKER
#define OUT_DIM 1124         // IN_DIM + NKER
#define KT 32                // K tiles of 32 (1024/32)
#define NT 320               // padded n-tiles (5120 cols; 313 real)

typedef short bf16x8 __attribute__((ext_vector_type(8)));
typedef float f32x4v __attribute__((ext_vector_type(4)));
typedef _Float16 h2 __attribute__((ext_vector_type(2)));

// d_ws layout: act fp16 @0 (2.56MB) | part @4MB (205KB) | Abuf @8MB (512KB) | Bbuf @16MB (10.5MB)

// ============ Kernel 0: prep — swizzle x and W into MFMA-fragment order (bf16) ============
// Fragment (for mfma_f32_16x16x32_bf16): lane l holds 8 k-contiguous elems at
// row/col (l&15), k-quad (l>>4). Stored as 1KB contiguous per frag -> the GEMM
// reads each whole fragment with ONE coalesced global b128 per lane.
// A-frags: f=(mt,kt): Abuf[f*512+l*8+e] = x[mt*16+(l&15)][kt*32+(l>>4)*8+e]
// B-frags: f=(nt,kt): Bbuf[f*512+l*8+e] = W[kt*32+(l>>4)*8+e][nt*16+(l&15)]
__global__ __launch_bounds__(256) void prep_kernel(const float* __restrict__ X,
                                                   const float* __restrict__ W,
                                                   __hip_bfloat16* __restrict__ Abuf,
                                                   __hip_bfloat16* __restrict__ Bbuf) {
    const int tid  = threadIdx.x;
    const int lane = tid & 63, w = tid >> 6;
    const int fl = lane & 15, fq = lane >> 4;
    const int b = blockIdx.x;

    if (b < 128) {                       // ---- A: 16mt x 32kt = 512 frags, 4/block ----
        const int f  = b * 4 + w;
        const int mt = f >> 5, kt = f & 31;
        const float* src = X + (mt * 16 + fl) * IN_DIM + kt * 32 + fq * 8;
        const float4 v0 = *(const float4*)(src);
        const float4 v1 = *(const float4*)(src + 4);
        __hip_bfloat16 t[8];
        t[0]=__float2bfloat16(v0.x); t[1]=__float2bfloat16(v0.y);
        t[2]=__float2bfloat16(v0.z); t[3]=__float2bfloat16(v0.w);
        t[4]=__float2bfloat16(v1.x); t[5]=__float2bfloat16(v1.y);
        t[6]=__float2bfloat16(v1.z); t[7]=__float2bfloat16(v1.w);
        *(bf16x8*)&Abuf[f * 512 + lane * 8] = *(const bf16x8*)t;
    } else {                             // ---- B: 320nt x 32kt = 10240 frags, 4/block ----
        const int f  = (b - 128) * 4 + w;
        const int nt = f >> 5, kt = f & 31;
        int n = nt * 16 + fl; if (n > ACT_N - 1) n = ACT_N - 1;   // clamp (stores masked later)
        const float* src = W + (kt * 32 + fq * 8) * ACT_N + n;
        __hip_bfloat16 t[8];
        #pragma unroll
        for (int e = 0; e < 8; ++e) t[e] = __float2bfloat16(src[e * ACT_N]);
        *(bf16x8*)&Bbuf[f * 512 + lane * 8] = *(const bf16x8*)t;
    }
}

// ============ Kernel 1: barrier-free frag-streaming MFMA GEMM ============
// grid 80 x 256thr (4 waves). Block tile 128M x 128N, wave tile 64x64 =
// 4mt x 4nt frags (16 f32x4 acc). Main loop: 8 coalesced b128 loads + 16 MFMA
// per kt — no LDS, no __syncthreads, no vmcnt(0) drain; compiler free to
// hoist next-kt loads across MFMAs (all inputs __restrict__ read-only).
// XCD swizzle: the 2 m-blocks sharing one W column-slice differ by 8 in id.
__global__ __launch_bounds__(256) void gemm_frag_kernel(const __hip_bfloat16* __restrict__ Abuf,
                                                        const __hip_bfloat16* __restrict__ Bbuf,
                                                        __half* __restrict__ act) {
    const int tid  = threadIdx.x;
    const int lane = tid & 63, w = tid >> 6;
    const int fl = lane & 15, fq = lane >> 4;
    const int id  = blockIdx.x;                  // 0..79
    const int ntb = (id >> 4) * 8 + (id & 7);    // 0..39
    const int mb  = (id >> 3) & 1;               // 0..1
    const int mt0 = mb * 8 + (w & 1) * 4;        // wave's first mt (16 total)
    const int nt0 = ntb * 8 + (w >> 1) * 4;      // wave's first nt (320 total)

    const __hip_bfloat16* ab[4];
    const __hip_bfloat16* bb[4];
    #pragma unroll
    for (int i = 0; i < 4; ++i) {
        ab[i] = Abuf + ((mt0 + i) * KT) * 512 + lane * 8;
        bb[i] = Bbuf + ((nt0 + i) * KT) * 512 + lane * 8;
    }

    f32x4v acc[4][4] = {};

    #pragma unroll 4
    for (int kt = 0; kt < KT; ++kt) {
        bf16x8 af[4], bf[4];
        #pragma unroll
        for (int i = 0; i < 4; ++i) af[i] = *(const bf16x8*)(ab[i] + kt * 512);
        #pragma unroll
        for (int i = 0; i < 4; ++i) bf[i] = *(const bf16x8*)(bb[i] + kt * 512);
        #pragma unroll
        for (int i = 0; i < 4; ++i)
            #pragma unroll
            for (int j = 0; j < 4; ++j)
                acc[i][j] = __builtin_amdgcn_mfma_f32_16x16x32_bf16(af[i], bf[j], acc[i][j], 0, 0, 0);
    }

    // epilogue: C/D layout col = lane&15, row = (lane>>4)*4 + reg
    #pragma unroll
    for (int i = 0; i < 4; ++i) {
        const int row0 = (mt0 + i) * 16 + fq * 4;
        #pragma unroll
        for (int j = 0; j < 4; ++j) {
            const int col = (nt0 + j) * 16 + fl;
            if (col < ACT_N) {
                #pragma unroll
                for (int r = 0; r < 4; ++r)
                    act[(row0 + r) * ACT_N + col] = __float2half(acc[i][j][r]);
            }
        }
    }
}

// ============ Kernel 2: pairwise L1 -> exp -> sum -> partial features ============
// (unchanged from round 5 — correct, est ~8-10 µs)
// Precision: diagonal |a-a|=0 -> exp(0)=1 exact in fp16; off-diagonal ~1e-31.
#define PKACC(r, m, acc) { h2 dd = __builtin_bit_cast(h2, (uint)(m)) - __builtin_bit_cast(h2, (uint)(r)); \
    uint uu = __builtin_bit_cast(uint, dd) & 0x7FFF7FFFu;                                                \
    acc = acc + __builtin_bit_cast(h2, uu); }

__global__ __launch_bounds__(256) void pairwise_kernel(const __half* __restrict__ act,
                                                       float* __restrict__ part) {
    const int k  = blockIdx.x;
    const int ib = blockIdx.y * 128;        // i-half base
    const int jb = blockIdx.z * 128;        // j-half base
    __shared__ __attribute__((aligned(16))) __half S[256 * 56];   // 28672 B
    __shared__ float P[4 * 128];
    const int tid = threadIdx.x;

    const ushort* __restrict__ src = (const ushort*)act + k * DKER;
    for (int idx = tid; idx < 256 * 32; idx += 256) {
        const int j = idx >> 5, d = idx & 31;
        if (d < 28) {
            uint v = 0u;
            if (d < 25) v = *(const uint*)(src + j * ACT_N + d * 2);
            *(uint*)&S[j * 56 + d * 2] = v;
        }
    }
    __syncthreads();

    const int lane = tid & 63, w = tid >> 6;

    uint my1[28], my2[28];
    {
        const uint* r1 = (const uint*)&S[(ib + lane) * 56];
        const uint* r2 = (const uint*)&S[(ib + 64 + lane) * 56];
        #pragma unroll
        for (int d = 0; d < 28; ++d) { my1[d] = r1[d]; my2[d] = r2[d]; }
    }

    const h2 kOne = { (_Float16)1.0f, (_Float16)1.0f };
    float sA = 0.f, sB = 0.f;
    const int j0 = jb + w * 32;
    for (int jj = 0; jj < 32; ++jj) {
        const uint4* row4 = (const uint4*)&S[(j0 + jj) * 56];   // uniform across wave
        h2 cA0 = {0, 0}, cA1 = {0, 0}, cB0 = {0, 0}, cB1 = {0, 0};
        #pragma unroll
        for (int q = 0; q < 7; ++q) {
            const uint4 rv = row4[q];
            PKACC(rv.x, my1[4*q+0], cA0) PKACC(rv.y, my1[4*q+1], cA1)
            PKACC(rv.z, my1[4*q+2], cA0) PKACC(rv.w, my1[4*q+3], cA1)
            PKACC(rv.x, my2[4*q+0], cB0) PKACC(rv.y, my2[4*q+1], cB1)
            PKACC(rv.z, my2[4*q+2], cB0) PKACC(rv.w, my2[4*q+3], cB1)
        }
        const float l1A = __builtin_amdgcn_fdot2(cA0 + cA1, kOne, 0.f, false);
        const float l1B = __builtin_amdgcn_fdot2(cB0 + cB1, kOne, 0.f, false);
        sA += __expf(-l1A);
        sB += __expf(-l1B);
    }

    P[w * 128 + lane]      = sA;
    P[w * 128 + 64 + lane] = sB;
    __syncthreads();
    if (tid < 128) {
        float f = 0.f;
        #pragma unroll
        for (int g = 0; g < 4; ++g) f += P[g * 128 + tid];
        part[((k * 2 + blockIdx.z) * 2 + blockIdx.y) * 128 + tid] = f;
    }
}

// ============ Kernel 3: copy x + combine j-half partials into out ============
__global__ __launch_bounds__(256) void combine_kernel(const float* __restrict__ x,
                                                      const float* __restrict__ part,
                                                      float* __restrict__ out) {
    const int i = blockIdx.x;
    const int t = threadIdx.x;
    *(float4*)&out[i * OUT_DIM + t * 4] = *(const float4*)&x[i * IN_DIM + t * 4];
    if (t < NKER) {
        const int ih = i >> 7, il = i & 127;
        const float f = part[((t * 2 + 0) * 2 + ih) * 128 + il]
                      + part[((t * 2 + 1) * 2 + ih) * 128 + il];
        out[i * OUT_DIM + IN_DIM + t] = f;
    }
}

extern "C" void kernel_launch(void* const* d_in, const int* in_sizes, int n_in,
                              void* d_out, int out_size, void* d_ws, size_t ws_size,
                              hipStream_t stream) {
    const float* x = (const float*)d_in[0];       // 256x1024
    const float* w = (const float*)d_in[1];       // 1024x5000
    float* out = (float*)d_out;                   // 256x1124
    __half* act = (__half*)d_ws;                                    // @0    2.56 MB
    float* part = (float*)((char*)d_ws + (4 << 20));                // @4MB  205 KB
    __hip_bfloat16* Abuf = (__hip_bfloat16*)((char*)d_ws + (8 << 20));   // @8MB  512 KB
    __hip_bfloat16* Bbuf = (__hip_bfloat16*)((char*)d_ws + (16 << 20));  // @16MB 10.5 MB

    prep_kernel<<<dim3(128 + 2560), dim3(256), 0, stream>>>(x, w, Abuf, Bbuf);
    gemm_frag_kernel<<<dim3(80), dim3(256), 0, stream>>>(Abuf, Bbuf, act);
    pairwise_kernel<<<dim3(NKER, 2, 2), dim3(256), 0, stream>>>(act, part);
    combine_kernel<<<dim3(256), dim3(256), 0, stream>>>(x, part, out);
}

// Round 7
// 128.394 us; speedup vs baseline: 1.0087x; 1.0087x over previous
//
#include <hip/hip_runtime.h>
#include <hip/hip_bf16.h>
#include <hip/hip_fp16.h>

// Problem constants
#define BATCH 256
#define IN_DIM 1024
#define NKER 100
#define DKER 50
#define ACT_N 5000           // NKER*DKER
#define OUT_DIM 1124         // IN_DIM + NKER
#define NPAD 5120            // W columns padded to 80 n-tiles of 64

typedef short bf16x8 __attribute__((ext_vector_type(8)));
typedef float f32x4v __attribute__((ext_vector_type(4)));
typedef _Float16 h2 __attribute__((ext_vector_type(2)));

// d_ws: act fp16 @0 (2.56MB) | part @4MB (205KB) | Xb @8MB (512KB) | Wt @16MB (10.5MB)

// ============ Kernel 0: prep — X->bf16, W->bf16 transposed [n][k] ============
// Wt rows are k-contiguous so the GEMM's global_load_lds can fetch a whole
// 16B B-fragment slice per lane. Reads are 256B wave-coalesced.
__global__ __launch_bounds__(256) void prep_kernel(const float* __restrict__ X,
                                                   const float* __restrict__ W,
                                                   __hip_bfloat16* __restrict__ Xb,
                                                   __hip_bfloat16* __restrict__ Wt) {
    const int b = blockIdx.x, t = threadIdx.x;
    if (b < 1280) {                       // W transpose: block = 64n x 64k tile
        const int nb = b >> 4, kb = b & 15;
        const int n  = nb * 64 + (t & 63);
        const int k0 = kb * 64 + (t >> 6) * 16;
        const int ns = n < ACT_N ? n : ACT_N - 1;   // clamp pad rows (masked in gemm epilogue)
        const float* src = W + ns;
        __hip_bfloat16 tmp[16];
        #pragma unroll
        for (int e = 0; e < 16; ++e)
            tmp[e] = __float2bfloat16(src[(size_t)(k0 + e) * ACT_N]);
        *(bf16x8*)&Wt[n * 1024 + k0 + 0] = *(const bf16x8*)&tmp[0];
        *(bf16x8*)&Wt[n * 1024 + k0 + 8] = *(const bf16x8*)&tmp[8];
    } else {                              // X convert: contiguous
        const int idx = (b - 1280) * 4096 + t * 16;
        const float4* s = (const float4*)(X + idx);
        const float4 v0 = s[0], v1 = s[1], v2 = s[2], v3 = s[3];
        __hip_bfloat16 tmp[16];
        tmp[0]=__float2bfloat16(v0.x); tmp[1]=__float2bfloat16(v0.y); tmp[2]=__float2bfloat16(v0.z); tmp[3]=__float2bfloat16(v0.w);
        tmp[4]=__float2bfloat16(v1.x); tmp[5]=__float2bfloat16(v1.y); tmp[6]=__float2bfloat16(v1.z); tmp[7]=__float2bfloat16(v1.w);
        tmp[8]=__float2bfloat16(v2.x); tmp[9]=__float2bfloat16(v2.y); tmp[10]=__float2bfloat16(v2.z); tmp[11]=__float2bfloat16(v2.w);
        tmp[12]=__float2bfloat16(v3.x); tmp[13]=__float2bfloat16(v3.y); tmp[14]=__float2bfloat16(v3.z); tmp[15]=__float2bfloat16(v3.w);
        *(bf16x8*)&Xb[idx + 0] = *(const bf16x8*)&tmp[0];
        *(bf16x8*)&Xb[idx + 8] = *(const bf16x8*)&tmp[8];
    }
}

// ============ Kernel 1: MFMA GEMM with async global->LDS frag staging ============
// grid 320 (1.25 blk/CU), 256 thr (4 waves). Tile 64M x 64N, BK=64.
// LDS = 2 buffers x 16 frags x 1KB (frag order: lane*16B — the native
// global_load_lds scatter AND the conflict-free ds_read_b128 pattern).
// Double-buffered: loads for iter it+1 issue right after the barrier of iter
// it, so the next barrier's vmcnt(0) drain waits on loads one full compute
// phase old. No VGPR round-trip, no cvt in the hot loop.
#define GL2LDS(g, l) __builtin_amdgcn_global_load_lds(                      \
    (const __attribute__((address_space(1))) void*)(g),                     \
    (__attribute__((address_space(3))) void*)(l), 16, 0, 0)

__global__ __launch_bounds__(256) void gemm_kernel(const __hip_bfloat16* __restrict__ Xb,
                                                   const __hip_bfloat16* __restrict__ Wt,
                                                   __half* __restrict__ act) {
    __shared__ __attribute__((aligned(16))) __hip_bfloat16 Ls[2][16][512];
    const int tid = threadIdx.x, lane = tid & 63, w = tid >> 6;
    const int fl = lane & 15, fq = lane >> 4;
    // XCD swizzle: 4 m-blocks sharing one W column-slice differ by 8 in id.
    const int id = blockIdx.x;                     // 0..319
    const int nb = (id & 7) + (id >> 5) * 8;       // 0..79
    const int mb = (id >> 3) & 3;                  // 0..3
    const int m0 = mb * 64, n0 = nb * 64;

    // this wave stages frags f = w*4 .. w*4+3  (f<8: A, else B)
    const __hip_bfloat16* gsrc[4];
    #pragma unroll
    for (int c = 0; c < 4; ++c) {
        const int f = w * 4 + c;
        if (f < 8) {
            const int mt = f >> 1, kq = f & 1;
            gsrc[c] = Xb + (m0 + mt * 16 + fl) * 1024 + kq * 32 + fq * 8;
        } else {
            const int g = f - 8, nt = g >> 1, kq = g & 1;
            gsrc[c] = Wt + (n0 + nt * 16 + fl) * 1024 + kq * 32 + fq * 8;
        }
    }
    const int fbase = w * 4;

    f32x4v acc[2][2] = {};

    // prologue: stage k-tile 0 into buffer 0
    #pragma unroll
    for (int c = 0; c < 4; ++c) GL2LDS(gsrc[c], &Ls[0][fbase + c][0]);

    const int aw = 2 * (w & 1);     // wave's A frag-pair base (mt)
    const int bw = 2 * (w >> 1);    // wave's B frag-pair base (nt)

    for (int it = 0; it < 16; ++it) {
        const int cur = it & 1;
        __syncthreads();            // drains the loads that filled buf[cur]
        if (it < 15) {
            #pragma unroll
            for (int c = 0; c < 4; ++c)
                GL2LDS(gsrc[c] + (it + 1) * 64, &Ls[cur ^ 1][fbase + c][0]);
        }
        #pragma unroll
        for (int kq = 0; kq < 2; ++kq) {
            bf16x8 af0 = *(const bf16x8*)&Ls[cur][(aw + 0) * 2 + kq][lane * 8];
            bf16x8 af1 = *(const bf16x8*)&Ls[cur][(aw + 1) * 2 + kq][lane * 8];
            bf16x8 bf0 = *(const bf16x8*)&Ls[cur][8 + (bw + 0) * 2 + kq][lane * 8];
            bf16x8 bf1 = *(const bf16x8*)&Ls[cur][8 + (bw + 1) * 2 + kq][lane * 8];
            acc[0][0] = __builtin_amdgcn_mfma_f32_16x16x32_bf16(af0, bf0, acc[0][0], 0, 0, 0);
            acc[0][1] = __builtin_amdgcn_mfma_f32_16x16x32_bf16(af0, bf1, acc[0][1], 0, 0, 0);
            acc[1][0] = __builtin_amdgcn_mfma_f32_16x16x32_bf16(af1, bf0, acc[1][0], 0, 0, 0);
            acc[1][1] = __builtin_amdgcn_mfma_f32_16x16x32_bf16(af1, bf1, acc[1][1], 0, 0, 0);
        }
    }

    // epilogue: C/D layout col = lane&15, row = (lane>>4)*4 + reg
    #pragma unroll
    for (int i = 0; i < 2; ++i) {
        const int row0 = m0 + (aw + i) * 16 + fq * 4;
        #pragma unroll
        for (int j = 0; j < 2; ++j) {
            const int col = n0 + (bw + j) * 16 + fl;
            if (col < ACT_N) {
                #pragma unroll
                for (int r = 0; r < 4; ++r)
                    act[(row0 + r) * ACT_N + col] = __float2half(acc[i][j][r]);
            }
        }
    }
}

// ============ Kernel 2: pairwise L1 -> exp -> sum -> partial features ============
// Diagonal |a-a|=0 -> exp(0)=1 exact in fp16; off-diagonal ~1e-31 (absmax=0 observed).
#define PKACC(r, m, acc) { h2 dd = __builtin_bit_cast(h2, (uint)(m)) - __builtin_bit_cast(h2, (uint)(r)); \
    uint uu = __builtin_bit_cast(uint, dd) & 0x7FFF7FFFu;                                                \
    acc = acc + __builtin_bit_cast(h2, uu); }

__global__ __launch_bounds__(256) void pairwise_kernel(const __half* __restrict__ act,
                                                       float* __restrict__ part) {
    const int k  = blockIdx.x;
    const int ib = blockIdx.y * 128;
    const int jb = blockIdx.z * 128;
    __shared__ __attribute__((aligned(16))) __half S[256 * 56];
    __shared__ float P[4 * 128];
    const int tid = threadIdx.x;

    const ushort* __restrict__ src = (const ushort*)act + k * DKER;
    for (int idx = tid; idx < 256 * 32; idx += 256) {
        const int j = idx >> 5, d = idx & 31;
        if (d < 28) {
            uint v = 0u;
            if (d < 25) v = *(const uint*)(src + j * ACT_N + d * 2);
            *(uint*)&S[j * 56 + d * 2] = v;
        }
    }
    __syncthreads();

    const int lane = tid & 63, w = tid >> 6;

    uint my1[28], my2[28];
    {
        const uint* r1 = (const uint*)&S[(ib + lane) * 56];
        const uint* r2 = (const uint*)&S[(ib + 64 + lane) * 56];
        #pragma unroll
        for (int d = 0; d < 28; ++d) { my1[d] = r1[d]; my2[d] = r2[d]; }
    }

    const h2 kOne = { (_Float16)1.0f, (_Float16)1.0f };
    float sA = 0.f, sB = 0.f;
    const int j0 = jb + w * 32;
    for (int jj = 0; jj < 32; ++jj) {
        const uint4* row4 = (const uint4*)&S[(j0 + jj) * 56];
        h2 cA0 = {0, 0}, cA1 = {0, 0}, cB0 = {0, 0}, cB1 = {0, 0};
        #pragma unroll
        for (int q = 0; q < 7; ++q) {
            const uint4 rv = row4[q];
            PKACC(rv.x, my1[4*q+0], cA0) PKACC(rv.y, my1[4*q+1], cA1)
            PKACC(rv.z, my1[4*q+2], cA0) PKACC(rv.w, my1[4*q+3], cA1)
            PKACC(rv.x, my2[4*q+0], cB0) PKACC(rv.y, my2[4*q+1], cB1)
            PKACC(rv.z, my2[4*q+2], cB0) PKACC(rv.w, my2[4*q+3], cB1)
        }
        const float l1A = __builtin_amdgcn_fdot2(cA0 + cA1, kOne, 0.f, false);
        const float l1B = __builtin_amdgcn_fdot2(cB0 + cB1, kOne, 0.f, false);
        sA += __expf(-l1A);
        sB += __expf(-l1B);
    }

    P[w * 128 + lane]      = sA;
    P[w * 128 + 64 + lane] = sB;
    __syncthreads();
    if (tid < 128) {
        float f = 0.f;
        #pragma unroll
        for (int g = 0; g < 4; ++g) f += P[g * 128 + tid];
        part[((k * 2 + blockIdx.z) * 2 + blockIdx.y) * 128 + tid] = f;
    }
}

// ============ Kernel 3: copy x + combine partials into out ============
__global__ __launch_bounds__(256) void combine_kernel(const float* __restrict__ x,
                                                      const float* __restrict__ part,
                                                      float* __restrict__ out) {
    const int i = blockIdx.x;
    const int t = threadIdx.x;
    *(float4*)&out[i * OUT_DIM + t * 4] = *(const float4*)&x[i * IN_DIM + t * 4];
    if (t < NKER) {
        const int ih = i >> 7, il = i & 127;
        const float f = part[((t * 2 + 0) * 2 + ih) * 128 + il]
                      + part[((t * 2 + 1) * 2 + ih) * 128 + il];
        out[i * OUT_DIM + IN_DIM + t] = f;
    }
}

extern "C" void kernel_launch(void* const* d_in, const int* in_sizes, int n_in,
                              void* d_out, int out_size, void* d_ws, size_t ws_size,
                              hipStream_t stream) {
    const float* x = (const float*)d_in[0];       // 256x1024
    const float* w = (const float*)d_in[1];       // 1024x5000
    float* out = (float*)d_out;                   // 256x1124
    __half* act = (__half*)d_ws;                                         // @0    2.56 MB
    float* part = (float*)((char*)d_ws + (4 << 20));                     // @4MB  205 KB
    __hip_bfloat16* Xb = (__hip_bfloat16*)((char*)d_ws + (8 << 20));     // @8MB  512 KB
    __hip_bfloat16* Wt = (__hip_bfloat16*)((char*)d_ws + (16 << 20));    // @16MB 10.49 MB

    prep_kernel<<<dim3(1344), dim3(256), 0, stream>>>(x, w, Xb, Wt);
    gemm_kernel<<<dim3(320), dim3(256), 0, stream>>>(Xb, Wt, act);
    pairwise_kernel<<<dim3(NKER, 2, 2), dim3(256), 0, stream>>>(act, part);
    combine_kernel<<<dim3(256), dim3(256), 0, stream>>>(x, part, out);
}

// Round 8
// 114.408 us; speedup vs baseline: 1.1320x; 1.1222x over previous
//
#include <hip/hip_runtime.h>
#include <hip/hip_bf16.h>
#include <hip/hip_fp16.h>

// Problem constants
#define BATCH 256
#define IN_DIM 1024
#define NKER 100
#define DKER 50
#define ACT_N 5000           // NKER*DKER
#define OUT_DIM 1124         // IN_DIM + NKER

typedef short bf16x8 __attribute__((ext_vector_type(8)));
typedef float f32x4v __attribute__((ext_vector_type(4)));
typedef _Float16 h2 __attribute__((ext_vector_type(2)));

// ============ Kernel 1: bf16 MFMA GEMM  act = x @ W  (fp32 in, fp16 out) ============
// Verbatim round-4 internals (best measured total). Tile 32(M) x 64(N), BK=128,
// grid 79x8 = 632 blocks (~2.5 blk/CU), 256 thr. Register-prefetch double
// buffer; inline fp32->bf16 cvt; fp16 epilogue store.
#define BKK 128
#define LDSB 136   // LDS row stride in bf16 (272B)

__global__ __launch_bounds__(256) void gemm_bf16_kernel(const float* __restrict__ X,
                                                        const float* __restrict__ W,
                                                        __half* __restrict__ act) {
    constexpr int K = IN_DIM, N = ACT_N;
    __shared__ __attribute__((aligned(16))) __hip_bfloat16 As[32 * LDSB];
    __shared__ __attribute__((aligned(16))) __hip_bfloat16 Bs[64 * LDSB];

    const int tid = threadIdx.x;
    // XCD swizzle: the 8 m-blocks sharing one W column-slice get ids equal
    // mod 8 and within 64 of each other -> same XCD -> W served from L2.
    const int id = blockIdx.x;                       // grid 640, 8 idle
    const int bx = (id & 7) + ((id >> 6) << 3);      // 0..79
    const int bm = (id >> 3) & 7;                    // 0..7
    if (bx >= 79) return;
    const int m0 = bm * 32, n0 = bx * 64;

    const int am = tid >> 3, aseg = tid & 7;         // A: row 0..31, 16-k segment
    const int bn = tid & 63, bseg = tid >> 6;        // B: col 0..63, 32-k segment
    const bool bvalid = (n0 + bn) < N;

    const int lane = tid & 63, w = tid >> 6;
    const int wm = (w & 1) * 16, wn = (w >> 1) * 32;
    const int fl = lane & 15, fq = lane >> 4;

    f32x4v acc0 = {0.f, 0.f, 0.f, 0.f}, acc1 = {0.f, 0.f, 0.f, 0.f};

    const float* Xp = X + (m0 + am) * K + aseg * 16;
    const float* Wp = W + (bseg * 32) * N + n0 + bn;

    // ---- prefetch iteration 0 into registers ----
    float4 a0 = *(const float4*)(Xp + 0);
    float4 a1 = *(const float4*)(Xp + 4);
    float4 a2 = *(const float4*)(Xp + 8);
    float4 a3 = *(const float4*)(Xp + 12);
    float bv[32];
    #pragma unroll
    for (int j = 0; j < 32; ++j) bv[j] = bvalid ? Wp[j * N] : 0.f;

    for (int k0 = 0; k0 < K; k0 += BKK) {
        __syncthreads();   // all waves done reading LDS of previous iteration

        // ---- cvt fp32->bf16, stage regs -> LDS ----
        __hip_bfloat16 at[16];
        at[0]=__float2bfloat16(a0.x); at[1]=__float2bfloat16(a0.y); at[2]=__float2bfloat16(a0.z); at[3]=__float2bfloat16(a0.w);
        at[4]=__float2bfloat16(a1.x); at[5]=__float2bfloat16(a1.y); at[6]=__float2bfloat16(a1.z); at[7]=__float2bfloat16(a1.w);
        at[8]=__float2bfloat16(a2.x); at[9]=__float2bfloat16(a2.y); at[10]=__float2bfloat16(a2.z); at[11]=__float2bfloat16(a2.w);
        at[12]=__float2bfloat16(a3.x); at[13]=__float2bfloat16(a3.y); at[14]=__float2bfloat16(a3.z); at[15]=__float2bfloat16(a3.w);
        *(bf16x8*)&As[am * LDSB + aseg * 16 + 0] = *(const bf16x8*)&at[0];
        *(bf16x8*)&As[am * LDSB + aseg * 16 + 8] = *(const bf16x8*)&at[8];

        __hip_bfloat16 bt[32];
        #pragma unroll
        for (int j = 0; j < 32; ++j) bt[j] = __float2bfloat16(bv[j]);
        #pragma unroll
        for (int q = 0; q < 4; ++q)
            *(bf16x8*)&Bs[bn * LDSB + bseg * 32 + q * 8] = *(const bf16x8*)&bt[q * 8];
        __syncthreads();

        // ---- issue next iteration's global loads (in flight during MFMA) ----
        if (k0 + BKK < K) {
            const float* Xn = Xp + k0 + BKK;
            a0 = *(const float4*)(Xn + 0);
            a1 = *(const float4*)(Xn + 4);
            a2 = *(const float4*)(Xn + 8);
            a3 = *(const float4*)(Xn + 12);
            const float* Wn = Wp + (k0 + BKK) * N;
            #pragma unroll
            for (int j = 0; j < 32; ++j) bv[j] = bvalid ? Wn[j * N] : 0.f;
        }

        // ---- MFMA: 4 k-steps of 32 ----
        #pragma unroll
        for (int kk = 0; kk < BKK; kk += 32) {
            bf16x8 af  = *(const bf16x8*)&As[(wm + fl) * LDSB + kk + fq * 8];
            bf16x8 bf0 = *(const bf16x8*)&Bs[(wn + fl) * LDSB + kk + fq * 8];
            bf16x8 bf1 = *(const bf16x8*)&Bs[(wn + 16 + fl) * LDSB + kk + fq * 8];
            acc0 = __builtin_amdgcn_mfma_f32_16x16x32_bf16(af, bf0, acc0, 0, 0, 0);
            acc1 = __builtin_amdgcn_mfma_f32_16x16x32_bf16(af, bf1, acc1, 0, 0, 0);
        }
    }

    // ---- epilogue: C/D layout col = lane&15, row = (lane>>4)*4 + reg ----
    const int row0 = m0 + wm + fq * 4;
    const int col0 = n0 + wn + fl;
    if (col0 < N) {
        #pragma unroll
        for (int r = 0; r < 4; ++r) act[(row0 + r) * N + col0] = __float2half(acc0[r]);
    }
    const int col1 = col0 + 16;
    if (col1 < N) {
        #pragma unroll
        for (int r = 0; r < 4; ++r) act[(row0 + r) * N + col1] = __float2half(acc1[r]);
    }
}

// ============ Kernel 2: FUSED pairwise + feature write + x-copy ============
// grid (100 k, 2 i-half) = 200 blocks, 512 threads (8 waves).
// Full j-range per block -> features written directly (no partials/combine
// kernel). Blocks with k<64 also copy 2 rows of x into out (1 float4/thread),
// overlapping the LDS-staging latency. Round-5 PKACC math: packed-fp16 |diff|
// accumulation (diagonal |a-a|=0 exact in fp16; off-diagonal exp ~1e-31).
#define PKACC(r, m, acc) { h2 dd = __builtin_bit_cast(h2, (uint)(m)) - __builtin_bit_cast(h2, (uint)(r)); \
    uint uu = __builtin_bit_cast(uint, dd) & 0x7FFF7FFFu;                                                \
    acc = acc + __builtin_bit_cast(h2, uu); }

__global__ __launch_bounds__(512) void pairwise_kernel(const __half* __restrict__ act,
                                                       const float* __restrict__ x,
                                                       float* __restrict__ out) {
    const int k  = blockIdx.x;
    const int ib = blockIdx.y * 128;        // i-half base
    __shared__ __attribute__((aligned(16))) __half S[256 * 56];   // 28672 B
    __shared__ float P[8 * 128];
    const int tid = threadIdx.x;

    // stage act[:, k*50 : +50] as fp16, zero-padded to 56 halves/row
    const ushort* __restrict__ src = (const ushort*)act + k * DKER;
    for (int idx = tid; idx < 256 * 32; idx += 512) {
        const int j = idx >> 5, d = idx & 31;
        if (d < 28) {
            uint v = 0u;
            if (d < 25) v = *(const uint*)(src + j * ACT_N + d * 2);
            *(uint*)&S[j * 56 + d * 2] = v;
        }
    }

    // fold x->out copy into the first 64 k-blocks (2 rows each, 1 float4/thr)
    if (k < 64) {
        const int row = ib + k * 2 + (tid >> 8);     // 64 blocks x 2 rows = 128 rows per i-half
        const int c4  = tid & 255;
        *(float4*)&out[row * OUT_DIM + c4 * 4] = *(const float4*)&x[row * IN_DIM + c4 * 4];
    }
    __syncthreads();

    const int lane = tid & 63, w = tid >> 6;

    // my two rows in registers (28 dwords = 56 halves each)
    uint my1[28], my2[28];
    {
        const uint* r1 = (const uint*)&S[(ib + lane) * 56];
        const uint* r2 = (const uint*)&S[(ib + 64 + lane) * 56];
        #pragma unroll
        for (int d = 0; d < 28; ++d) { my1[d] = r1[d]; my2[d] = r2[d]; }
    }

    const h2 kOne = { (_Float16)1.0f, (_Float16)1.0f };
    float sA = 0.f, sB = 0.f;
    const int j0 = w * 32;                  // 8 waves x 32 j = 256 j
    for (int jj = 0; jj < 32; ++jj) {
        const uint4* row4 = (const uint4*)&S[(j0 + jj) * 56];   // uniform across wave
        h2 cA0 = {0, 0}, cA1 = {0, 0}, cB0 = {0, 0}, cB1 = {0, 0};
        #pragma unroll
        for (int q = 0; q < 7; ++q) {
            const uint4 rv = row4[q];
            PKACC(rv.x, my1[4*q+0], cA0) PKACC(rv.y, my1[4*q+1], cA1)
            PKACC(rv.z, my1[4*q+2], cA0) PKACC(rv.w, my1[4*q+3], cA1)
            PKACC(rv.x, my2[4*q+0], cB0) PKACC(rv.y, my2[4*q+1], cB1)
            PKACC(rv.z, my2[4*q+2], cB0) PKACC(rv.w, my2[4*q+3], cB1)
        }
        const float l1A = __builtin_amdgcn_fdot2(cA0 + cA1, kOne, 0.f, false);
        const float l1B = __builtin_amdgcn_fdot2(cB0 + cB1, kOne, 0.f, false);
        sA += __expf(-l1A);
        sB += __expf(-l1B);
    }

    P[w * 128 + lane]      = sA;
    P[w * 128 + 64 + lane] = sB;
    __syncthreads();
    if (tid < 128) {
        float f = 0.f;
        #pragma unroll
        for (int g = 0; g < 8; ++g) f += P[g * 128 + tid];
        out[(ib + tid) * OUT_DIM + IN_DIM + k] = f;
    }
}

extern "C" void kernel_launch(void* const* d_in, const int* in_sizes, int n_in,
                              void* d_out, int out_size, void* d_ws, size_t ws_size,
                              hipStream_t stream) {
    const float* x = (const float*)d_in[0];       // 256x1024
    const float* w = (const float*)d_in[1];       // 1024x5000
    float* out = (float*)d_out;                   // 256x1124
    __half* act = (__half*)d_ws;                  // 256x5000 fp16 (2.56 MB)

    gemm_bf16_kernel<<<dim3(640), dim3(256), 0, stream>>>(x, w, act);
    pairwise_kernel<<<dim3(NKER, 2), dim3(512), 0, stream>>>(act, x, out);
}